// Round 19
// baseline (146.126 us; speedup 1.0000x reference)
//
#include <hip/hip_runtime.h>

#define HW 65536
#define CH 64
#define NPIXF 4194304.0f

typedef __attribute__((ext_vector_type(8))) short short8;
typedef __attribute__((ext_vector_type(4))) short short4v;
typedef __attribute__((ext_vector_type(8))) __bf16 bf16x8;
typedef __attribute__((ext_vector_type(4))) float f32x4;
typedef __attribute__((ext_vector_type(2))) float f32x2;

__device__ __forceinline__ unsigned short f2bf(float f) {
  unsigned int u = __builtin_bit_cast(unsigned int, f);
  u += 0x7FFFu + ((u >> 16) & 1u);
  return (unsigned short)(u >> 16);
}
__device__ __forceinline__ short cvt1(float f) {
  return __builtin_bit_cast(short, (__bf16)f);
}
__device__ __forceinline__ float fastrcp(float f) {
  return __builtin_amdgcn_rcpf(f);
}
__device__ __forceinline__ int swz(int p, int cc) { return cc ^ ((p ^ (p >> 3)) & 7); }

// ws layout (floats):
//   stats: wsf[16*s+0]=sum_x +1=sumsq_x +2=sum_h +3=sumsq_h  (64B line/sample, memset-zeroed)
//   consts: u1=wsf[256..319]  v1=wsf[320..383]  u2=wsf[384..399]  v2=wsf[400..415]
//   a1 bf16[64][64] @2048, a2 bf16[16][64] @10240.  need = 16384 B.

// ---- k1: x stats; launch_bounds(256,4) -> VGPR cap 64 (deep load pipeline,
//          still <=64 so full 32 waves/CU). Block (0,0) preps weights. ----
__global__ __launch_bounds__(256, 4) void k1(
    const float* __restrict__ x,
    const float* __restrict__ w1, const float* __restrict__ b1,
    const float* __restrict__ s1, const float* __restrict__ gb1,
    const float* __restrict__ w2, const float* __restrict__ b2,
    const float* __restrict__ s2, const float* __restrict__ gb2,
    float* __restrict__ wsf,
    unsigned short* __restrict__ a1, unsigned short* __restrict__ a2) {
  __shared__ float red[8];
  const int tid = threadIdx.x;
  const int l = tid & 63, w = tid >> 6;
  const int b = blockIdx.y;

  if (blockIdx.x == 0 && b == 0) {
    {
      int o = tid >> 2, q = tid & 3;
      float u = 0.f, v = 0.f;
      unsigned short loc[16];
#pragma unroll
      for (int i = 0; i < 16; ++i) {
        int c = q * 16 + i;
        float wv = w1[o * 64 + c];
        float wsc = wv * s1[c];
        loc[i] = f2bf(wsc);
        u += wsc;
        v += wv * gb1[c];
      }
      *(short8*)(a1 + o * 64 + q * 16) = *(short8*)loc;
      *(short8*)(a1 + o * 64 + q * 16 + 8) = *(short8*)(loc + 8);
      u += __shfl_xor(u, 1, 64); u += __shfl_xor(u, 2, 64);
      v += __shfl_xor(v, 1, 64); v += __shfl_xor(v, 2, 64);
      if (q == 0) { wsf[256 + o] = u; wsf[320 + o] = b1[o] + v; }
    }
    if (tid < 64) {
      int o = tid >> 2, q = tid & 3;
      float u = 0.f, v = 0.f;
      unsigned short loc[16];
#pragma unroll
      for (int i = 0; i < 16; ++i) {
        int c = q * 16 + i;
        float wv = (o < 6) ? w2[o * 64 + c] : 0.f;
        float wsc = wv * s2[c];
        loc[i] = f2bf(wsc);
        u += wsc;
        v += wv * gb2[c];
      }
      *(short8*)(a2 + o * 64 + q * 16) = *(short8*)loc;
      *(short8*)(a2 + o * 64 + q * 16 + 8) = *(short8*)(loc + 8);
      u += __shfl_xor(u, 1, 64); u += __shfl_xor(u, 2, 64);
      v += __shfl_xor(v, 1, 64); v += __shfl_xor(v, 2, 64);
      if (q == 0) { wsf[384 + o] = u; wsf[400 + o] = ((o < 6) ? b2[o] : 0.f) + v; }
    }
  }

  const f32x4* xb = (const f32x4*)(x + (size_t)b * CH * HW);
  const f32x4* p = xb + (size_t)blockIdx.x * 8192 + tid;
  float s = 0.f, q = 0.f;
#pragma unroll
  for (int it = 0; it < 32; ++it) {
    f32x4 v = p[it * 256];
#pragma unroll
    for (int i = 0; i < 4; ++i) { float f = v[i]; s += f; q += f * f; }
  }
#pragma unroll
  for (int off = 32; off > 0; off >>= 1) {
    s += __shfl_down(s, off, 64);
    q += __shfl_down(q, off, 64);
  }
  if (l == 0) { red[w] = s; red[4 + w] = q; }
  __syncthreads();
  if (tid == 0) {
    atomicAdd(wsf + 16 * b + 0, red[0] + red[1] + red[2] + red[3]);
    atomicAdd(wsf + 16 * b + 1, red[4] + red[5] + red[6] + red[7]);
  }
}

// ---- k2: low-VGPR many-wave pipeline; 512 px/block (8 subtiles) to amortize
//          per-block weight staging. ~20KB LDS, <=64 VGPR -> 8 blocks/CU. ----
__global__ __launch_bounds__(256, 4) void k2(const float* __restrict__ x,
                                             const unsigned short* __restrict__ a1,
                                             const unsigned short* __restrict__ a2,
                                             const float* __restrict__ wsf,
                                             float* __restrict__ wstat,
                                             float* __restrict__ out) {
  __shared__ __align__(16) unsigned char buf[64 * 128];   // x/h tile (8 KB)
  __shared__ __align__(16) unsigned char a1L[64 * 144];   // a1, pitch 144 (9.2 KB)
  __shared__ __align__(16) unsigned char a2L[16 * 144];   // a2, pitch 144 (2.3 KB)
  __shared__ float c1s[64];
  __shared__ float red[8];
  const int tid = threadIdx.x;
  const int l = tid & 63, w = tid >> 6;
  const int s = 15 - blockIdx.y;                  // reverse sample order
  const int pbase = (127 - blockIdx.x) * 512;     // 512 px per block, reverse
  const float* xb = x + (size_t)s * CH * HW;

  const float m1 = wsf[16 * s + 0] / NPIXF;
  const float rs1 = rsqrtf(wsf[16 * s + 1] / NPIXF - m1 * m1 + 1e-6f);

  // stage a1/a2 into LDS (pitch 144B), c1 into LDS
  {
    int r = tid >> 2, q = tid & 3;
    *(f32x4*)(a1L + r * 144 + q * 32) =
        *(const f32x4*)((const unsigned char*)a1 + r * 128 + q * 32);
    *(f32x4*)(a1L + r * 144 + q * 32 + 16) =
        *(const f32x4*)((const unsigned char*)a1 + r * 128 + q * 32 + 16);
  }
  if (tid < 64) {
    int r = tid >> 2, q = tid & 3;
    *(f32x4*)(a2L + r * 144 + q * 32) =
        *(const f32x4*)((const unsigned char*)a2 + r * 128 + q * 32);
    *(f32x4*)(a2L + r * 144 + q * 32 + 16) =
        *(const f32x4*)((const unsigned char*)a2 + r * 128 + q * 32 + 16);
  }
  if (tid >= 64 && tid < 128) {
    int c = tid - 64;
    c1s[c] = wsf[320 + c] - rs1 * m1 * wsf[256 + c];
  }
  __syncthreads();

  // wave-private partition: wave strip = 16 px; lane = (ch-group l>>3, px (l&7)*2)
  const int c0g = l >> 3;
  const int c0 = c0g * 8;
  const int px2 = (l & 7) * 2;
  const int prow = w * 16;
  const int pl = prow + (l & 15);                 // fragment row (wave-private)
  const float* base = xb + (size_t)c0 * HW + pbase + prow + px2;
  float* ob = out + (size_t)s * 6 * HW;

  // prologue: load + stage subtile 0
  f32x2 v[8];
#pragma unroll
  for (int i = 0; i < 8; ++i) v[i] = *(const f32x2*)(base + (size_t)i * HW);
#pragma unroll
  for (int dp = 0; dp < 2; ++dp) {
    int p = prow + px2 + dp;
    short8 w8;
#pragma unroll
    for (int i = 0; i < 8; ++i) w8[i] = cvt1(v[i][dp]);
    *(short8*)(buf + p * 128 + swz(p, c0g) * 16) = w8;
  }

  float hs = 0.f, hq = 0.f;
#pragma unroll
  for (int j = 0; j < 8; ++j) {
    // issue next subtile's loads; they fly under this subtile's compute
    if (j < 7) {
#pragma unroll
      for (int i = 0; i < 8; ++i)
        v[i] = *(const f32x2*)(base + (size_t)i * HW + (j + 1) * 64);
    }

    // B-fragments (x rows, read before h overwrites them)
    bf16x8 bfr[2];
#pragma unroll
    for (int ks = 0; ks < 2; ++ks) {
      int cc = ks * 4 + (l >> 4);
      bfr[ks] = *(const bf16x8*)(buf + pl * 128 + swz(pl, cc) * 16);
    }

    // phase A: conv1 (weights streamed from LDS) + silu + h-stats -> same rows
#pragma unroll
    for (int mf = 0; mf < 4; ++mf) {
      const unsigned char* arow = a1L + (mf * 16 + (l & 15)) * 144 + (l >> 4) * 16;
      bf16x8 af0 = *(const bf16x8*)(arow);
      bf16x8 af1 = *(const bf16x8*)(arow + 64);
      f32x4 acc = {0.f, 0.f, 0.f, 0.f};
      acc = __builtin_amdgcn_mfma_f32_16x16x32_bf16(af0, bfr[0], acc, 0, 0, 0);
      acc = __builtin_amdgcn_mfma_f32_16x16x32_bf16(af1, bfr[1], acc, 0, 0, 0);
      const int o0 = mf * 16 + (l >> 4) * 4;
      f32x4 c1v = *(const f32x4*)(c1s + o0);
      short4v hv;
#pragma unroll
      for (int r = 0; r < 4; ++r) {
        float z = rs1 * acc[r] + c1v[r];
        float hh = z * fastrcp(1.f + __expf(-z));
        hs += hh; hq += hh * hh;
        hv[r] = cvt1(hh);
      }
      *(short4v*)(buf + pl * 128 + swz(pl, o0 >> 3) * 16 + (o0 & 7) * 2) = hv;
    }

    // phase B: conv2 (a2 from LDS) -> raw y
    {
      bf16x8 hfr[2];
#pragma unroll
      for (int ks = 0; ks < 2; ++ks) {
        int cc = ks * 4 + (l >> 4);
        hfr[ks] = *(const bf16x8*)(buf + pl * 128 + swz(pl, cc) * 16);
      }
      const unsigned char* arow2 = a2L + (l & 15) * 144 + (l >> 4) * 16;
      bf16x8 a2f0 = *(const bf16x8*)(arow2);
      bf16x8 a2f1 = *(const bf16x8*)(arow2 + 64);
      f32x4 acc = {0.f, 0.f, 0.f, 0.f};
      acc = __builtin_amdgcn_mfma_f32_16x16x32_bf16(a2f0, hfr[0], acc, 0, 0, 0);
      acc = __builtin_amdgcn_mfma_f32_16x16x32_bf16(a2f1, hfr[1], acc, 0, 0, 0);
      const int ob0 = (l >> 4) * 4;
      const int p = pbase + j * 64 + pl;
#pragma unroll
      for (int r = 0; r < 4; ++r) {
        int o = ob0 + r;
        if (o < 6) ob[(size_t)o * HW + p] = acc[r];
      }
    }

    // stage next subtile into the SAME rows (after phase B reads; in-wave order)
    if (j < 7) {
#pragma unroll
      for (int dp = 0; dp < 2; ++dp) {
        int p = prow + px2 + dp;
        short8 w8;
#pragma unroll
        for (int i = 0; i < 8; ++i) w8[i] = cvt1(v[i][dp]);
        *(short8*)(buf + p * 128 + swz(p, c0g) * 16) = w8;
      }
    }
  }

#pragma unroll
  for (int off = 32; off > 0; off >>= 1) {
    hs += __shfl_down(hs, off, 64);
    hq += __shfl_down(hq, off, 64);
  }
  if (l == 0) { red[w] = hs; red[4 + w] = hq; }
  __syncthreads();
  if (tid == 0) {
    atomicAdd(wstat + 16 * s + 2, red[0] + red[1] + red[2] + red[3]);
    atomicAdd(wstat + 16 * s + 3, red[4] + red[5] + red[6] + red[7]);
  }
}

// ---- k3: out = rs2*out + c2[o]  (in-place, elementwise) ----
__global__ __launch_bounds__(256) void k3(float* __restrict__ out,
                                          const float* __restrict__ wsf) {
  const int s = 15 - blockIdx.y;
  const float m2 = wsf[16 * s + 2] / NPIXF;
  const float rs2 = rsqrtf(wsf[16 * s + 3] / NPIXF - m2 * m2 + 1e-6f);
  float* ob = out + (size_t)s * 6 * HW;
#pragma unroll
  for (int it = 0; it < 4; ++it) {
    int f4 = blockIdx.x * 256 + threadIdx.x + it * 24576;  // < 98304
    int o = f4 >> 14;
    float c2 = wsf[400 + o] - rs2 * m2 * wsf[384 + o];
    f32x4* p = (f32x4*)ob + f4;
    f32x4 v = *p;
#pragma unroll
    for (int i = 0; i < 4; ++i) v[i] = rs2 * v[i] + c2;
    *p = v;
  }
}

extern "C" void kernel_launch(void* const* d_in, const int* in_sizes, int n_in,
                              void* d_out, int out_size, void* d_ws, size_t ws_size,
                              hipStream_t stream) {
  const float* x  = (const float*)d_in[0];
  const float* s1 = (const float*)d_in[1];
  const float* g1 = (const float*)d_in[2];
  const float* w1 = (const float*)d_in[3];
  const float* b1 = (const float*)d_in[4];
  const float* s2 = (const float*)d_in[5];
  const float* g2 = (const float*)d_in[6];
  const float* w2 = (const float*)d_in[7];
  const float* b2 = (const float*)d_in[8];
  float* out = (float*)d_out;
  float* wsf = (float*)d_ws;
  unsigned short* a1 = (unsigned short*)((char*)d_ws + 2048);
  unsigned short* a2 = (unsigned short*)((char*)d_ws + 10240);

  if (ws_size < 16384) return;

  hipMemsetAsync(d_ws, 0, 1024, stream);  // zero per-sample stat lines
  k1<<<dim3(128, 16), 256, 0, stream>>>(x, w1, b1, s1, g1, w2, b2, s2, g2, wsf, a1, a2);
  k2<<<dim3(128, 16), 256, 0, stream>>>(x, a1, a2, wsf, wsf, out);
  k3<<<dim3(96, 16), 256, 0, stream>>>(out, wsf);
}

// Round 20
// 119.690 us; speedup vs baseline: 1.2209x; 1.2209x over previous
//
#include <hip/hip_runtime.h>

#define HW 65536
#define CH 64
#define NPIXF 4194304.0f

typedef __attribute__((ext_vector_type(8))) short short8;
typedef __attribute__((ext_vector_type(4))) short short4v;
typedef __attribute__((ext_vector_type(8))) __bf16 bf16x8;
typedef __attribute__((ext_vector_type(4))) float f32x4;
typedef __attribute__((ext_vector_type(2))) float f32x2;

__device__ __forceinline__ unsigned short f2bf(float f) {
  unsigned int u = __builtin_bit_cast(unsigned int, f);
  u += 0x7FFFu + ((u >> 16) & 1u);
  return (unsigned short)(u >> 16);
}
__device__ __forceinline__ short cvt1(float f) {
  return __builtin_bit_cast(short, (__bf16)f);
}
__device__ __forceinline__ float fastrcp(float f) {
  return __builtin_amdgcn_rcpf(f);
}
__device__ __forceinline__ int swz(int p, int cc) { return cc ^ ((p ^ (p >> 3)) & 7); }

// ws layout (floats):
//   stats: wsf[16*s+0]=sum_x +1=sumsq_x +2=sum_h +3=sumsq_h  (64B line/sample, memset-zeroed)
//   consts: u1=wsf[256..319]  v1=wsf[320..383]  u2=wsf[384..399]  v2=wsf[400..415]
//   a1 bf16[64][64] @2048, a2 bf16[16][64] @10240.  need = 16384 B.

// ---- k1: x stats; launch_bounds(256,6) -> VGPR cap ~42 (deeper load pipeline
//          than cap 32, safely below the 64-VGPR occupancy step). ----
__global__ __launch_bounds__(256, 6) void k1(
    const float* __restrict__ x,
    const float* __restrict__ w1, const float* __restrict__ b1,
    const float* __restrict__ s1, const float* __restrict__ gb1,
    const float* __restrict__ w2, const float* __restrict__ b2,
    const float* __restrict__ s2, const float* __restrict__ gb2,
    float* __restrict__ wsf,
    unsigned short* __restrict__ a1, unsigned short* __restrict__ a2) {
  __shared__ float red[8];
  const int tid = threadIdx.x;
  const int l = tid & 63, w = tid >> 6;
  const int b = blockIdx.y;

  if (blockIdx.x == 0 && b == 0) {
    {
      int o = tid >> 2, q = tid & 3;
      float u = 0.f, v = 0.f;
      unsigned short loc[16];
#pragma unroll
      for (int i = 0; i < 16; ++i) {
        int c = q * 16 + i;
        float wv = w1[o * 64 + c];
        float wsc = wv * s1[c];
        loc[i] = f2bf(wsc);
        u += wsc;
        v += wv * gb1[c];
      }
      *(short8*)(a1 + o * 64 + q * 16) = *(short8*)loc;
      *(short8*)(a1 + o * 64 + q * 16 + 8) = *(short8*)(loc + 8);
      u += __shfl_xor(u, 1, 64); u += __shfl_xor(u, 2, 64);
      v += __shfl_xor(v, 1, 64); v += __shfl_xor(v, 2, 64);
      if (q == 0) { wsf[256 + o] = u; wsf[320 + o] = b1[o] + v; }
    }
    if (tid < 64) {
      int o = tid >> 2, q = tid & 3;
      float u = 0.f, v = 0.f;
      unsigned short loc[16];
#pragma unroll
      for (int i = 0; i < 16; ++i) {
        int c = q * 16 + i;
        float wv = (o < 6) ? w2[o * 64 + c] : 0.f;
        float wsc = wv * s2[c];
        loc[i] = f2bf(wsc);
        u += wsc;
        v += wv * gb2[c];
      }
      *(short8*)(a2 + o * 64 + q * 16) = *(short8*)loc;
      *(short8*)(a2 + o * 64 + q * 16 + 8) = *(short8*)(loc + 8);
      u += __shfl_xor(u, 1, 64); u += __shfl_xor(u, 2, 64);
      v += __shfl_xor(v, 1, 64); v += __shfl_xor(v, 2, 64);
      if (q == 0) { wsf[384 + o] = u; wsf[400 + o] = ((o < 6) ? b2[o] : 0.f) + v; }
    }
  }

  const f32x4* xb = (const f32x4*)(x + (size_t)b * CH * HW);
  const f32x4* p = xb + (size_t)blockIdx.x * 8192 + tid;
  float s = 0.f, q = 0.f;
#pragma unroll
  for (int it = 0; it < 32; ++it) {
    f32x4 v = p[it * 256];
#pragma unroll
    for (int i = 0; i < 4; ++i) { float f = v[i]; s += f; q += f * f; }
  }
#pragma unroll
  for (int off = 32; off > 0; off >>= 1) {
    s += __shfl_down(s, off, 64);
    q += __shfl_down(q, off, 64);
  }
  if (l == 0) { red[w] = s; red[4 + w] = q; }
  __syncthreads();
  if (tid == 0) {
    atomicAdd(wsf + 16 * b + 0, red[0] + red[1] + red[2] + red[3]);
    atomicAdd(wsf + 16 * b + 1, red[4] + red[5] + red[6] + red[7]);
  }
}

// ---- k2: low-VGPR many-wave pipeline (R18 verbatim). 64-px subtiles,
//          weights/consts in LDS, single 8KB x/h buffer, ~20KB LDS. ----
__global__ __launch_bounds__(256, 4) void k2(const float* __restrict__ x,
                                             const unsigned short* __restrict__ a1,
                                             const unsigned short* __restrict__ a2,
                                             const float* __restrict__ wsf,
                                             float* __restrict__ wstat,
                                             float* __restrict__ out) {
  __shared__ __align__(16) unsigned char buf[64 * 128];   // x/h tile (8 KB)
  __shared__ __align__(16) unsigned char a1L[64 * 144];   // a1, pitch 144 (9.2 KB)
  __shared__ __align__(16) unsigned char a2L[16 * 144];   // a2, pitch 144 (2.3 KB)
  __shared__ float c1s[64];
  __shared__ float red[8];
  const int tid = threadIdx.x;
  const int l = tid & 63, w = tid >> 6;
  const int s = 15 - blockIdx.y;                  // reverse sample order
  const int pbase = (255 - blockIdx.x) * 256;     // 256 px per block, reverse
  const float* xb = x + (size_t)s * CH * HW;

  const float m1 = wsf[16 * s + 0] / NPIXF;
  const float rs1 = rsqrtf(wsf[16 * s + 1] / NPIXF - m1 * m1 + 1e-6f);

  // stage a1/a2 into LDS (pitch 144B: +4-bank rotate per row), c1 into LDS
  {
    int r = tid >> 2, q = tid & 3;
    *(f32x4*)(a1L + r * 144 + q * 32) =
        *(const f32x4*)((const unsigned char*)a1 + r * 128 + q * 32);
    *(f32x4*)(a1L + r * 144 + q * 32 + 16) =
        *(const f32x4*)((const unsigned char*)a1 + r * 128 + q * 32 + 16);
  }
  if (tid < 64) {
    int r = tid >> 2, q = tid & 3;
    *(f32x4*)(a2L + r * 144 + q * 32) =
        *(const f32x4*)((const unsigned char*)a2 + r * 128 + q * 32);
    *(f32x4*)(a2L + r * 144 + q * 32 + 16) =
        *(const f32x4*)((const unsigned char*)a2 + r * 128 + q * 32 + 16);
  }
  if (tid >= 64 && tid < 128) {
    int c = tid - 64;
    c1s[c] = wsf[320 + c] - rs1 * m1 * wsf[256 + c];
  }
  __syncthreads();

  // wave-private partition: wave strip = 16 px; lane = (ch-group l>>3, px (l&7)*2)
  const int c0g = l >> 3;
  const int c0 = c0g * 8;
  const int px2 = (l & 7) * 2;
  const int prow = w * 16;
  const int pl = prow + (l & 15);                 // fragment row (wave-private)
  const float* base = xb + (size_t)c0 * HW + pbase + prow + px2;
  float* ob = out + (size_t)s * 6 * HW;

  // prologue: load + stage subtile 0
  f32x2 v[8];
#pragma unroll
  for (int i = 0; i < 8; ++i) v[i] = *(const f32x2*)(base + (size_t)i * HW);
#pragma unroll
  for (int dp = 0; dp < 2; ++dp) {
    int p = prow + px2 + dp;
    short8 w8;
#pragma unroll
    for (int i = 0; i < 8; ++i) w8[i] = cvt1(v[i][dp]);
    *(short8*)(buf + p * 128 + swz(p, c0g) * 16) = w8;
  }

  float hs = 0.f, hq = 0.f;
#pragma unroll
  for (int j = 0; j < 4; ++j) {
    // issue next subtile's loads; they fly under this subtile's compute
    if (j < 3) {
#pragma unroll
      for (int i = 0; i < 8; ++i)
        v[i] = *(const f32x2*)(base + (size_t)i * HW + (j + 1) * 64);
    }

    // B-fragments (x rows, read before h overwrites them)
    bf16x8 bfr[2];
#pragma unroll
    for (int ks = 0; ks < 2; ++ks) {
      int cc = ks * 4 + (l >> 4);
      bfr[ks] = *(const bf16x8*)(buf + pl * 128 + swz(pl, cc) * 16);
    }

    // phase A: conv1 (weights streamed from LDS) + silu + h-stats -> same rows
#pragma unroll
    for (int mf = 0; mf < 4; ++mf) {
      const unsigned char* arow = a1L + (mf * 16 + (l & 15)) * 144 + (l >> 4) * 16;
      bf16x8 af0 = *(const bf16x8*)(arow);
      bf16x8 af1 = *(const bf16x8*)(arow + 64);
      f32x4 acc = {0.f, 0.f, 0.f, 0.f};
      acc = __builtin_amdgcn_mfma_f32_16x16x32_bf16(af0, bfr[0], acc, 0, 0, 0);
      acc = __builtin_amdgcn_mfma_f32_16x16x32_bf16(af1, bfr[1], acc, 0, 0, 0);
      const int o0 = mf * 16 + (l >> 4) * 4;
      f32x4 c1v = *(const f32x4*)(c1s + o0);
      short4v hv;
#pragma unroll
      for (int r = 0; r < 4; ++r) {
        float z = rs1 * acc[r] + c1v[r];
        float hh = z * fastrcp(1.f + __expf(-z));
        hs += hh; hq += hh * hh;
        hv[r] = cvt1(hh);
      }
      *(short4v*)(buf + pl * 128 + swz(pl, o0 >> 3) * 16 + (o0 & 7) * 2) = hv;
    }

    // phase B: conv2 (a2 from LDS) -> raw y
    {
      bf16x8 hfr[2];
#pragma unroll
      for (int ks = 0; ks < 2; ++ks) {
        int cc = ks * 4 + (l >> 4);
        hfr[ks] = *(const bf16x8*)(buf + pl * 128 + swz(pl, cc) * 16);
      }
      const unsigned char* arow2 = a2L + (l & 15) * 144 + (l >> 4) * 16;
      bf16x8 a2f0 = *(const bf16x8*)(arow2);
      bf16x8 a2f1 = *(const bf16x8*)(arow2 + 64);
      f32x4 acc = {0.f, 0.f, 0.f, 0.f};
      acc = __builtin_amdgcn_mfma_f32_16x16x32_bf16(a2f0, hfr[0], acc, 0, 0, 0);
      acc = __builtin_amdgcn_mfma_f32_16x16x32_bf16(a2f1, hfr[1], acc, 0, 0, 0);
      const int ob0 = (l >> 4) * 4;
      const int p = pbase + j * 64 + pl;
#pragma unroll
      for (int r = 0; r < 4; ++r) {
        int o = ob0 + r;
        if (o < 6) ob[(size_t)o * HW + p] = acc[r];
      }
    }

    // stage next subtile into the SAME rows (after phase B reads; in-wave order)
    if (j < 3) {
#pragma unroll
      for (int dp = 0; dp < 2; ++dp) {
        int p = prow + px2 + dp;
        short8 w8;
#pragma unroll
        for (int i = 0; i < 8; ++i) w8[i] = cvt1(v[i][dp]);
        *(short8*)(buf + p * 128 + swz(p, c0g) * 16) = w8;
      }
    }
  }

#pragma unroll
  for (int off = 32; off > 0; off >>= 1) {
    hs += __shfl_down(hs, off, 64);
    hq += __shfl_down(hq, off, 64);
  }
  if (l == 0) { red[w] = hs; red[4 + w] = hq; }
  __syncthreads();
  if (tid == 0) {
    atomicAdd(wstat + 16 * s + 2, red[0] + red[1] + red[2] + red[3]);
    atomicAdd(wstat + 16 * s + 3, red[4] + red[5] + red[6] + red[7]);
  }
}

// ---- k3: out = rs2*out + c2[o]  (in-place, elementwise) ----
__global__ __launch_bounds__(256) void k3(float* __restrict__ out,
                                          const float* __restrict__ wsf) {
  const int s = 15 - blockIdx.y;
  const float m2 = wsf[16 * s + 2] / NPIXF;
  const float rs2 = rsqrtf(wsf[16 * s + 3] / NPIXF - m2 * m2 + 1e-6f);
  float* ob = out + (size_t)s * 6 * HW;
#pragma unroll
  for (int it = 0; it < 4; ++it) {
    int f4 = blockIdx.x * 256 + threadIdx.x + it * 24576;  // < 98304
    int o = f4 >> 14;
    float c2 = wsf[400 + o] - rs2 * m2 * wsf[384 + o];
    f32x4* p = (f32x4*)ob + f4;
    f32x4 v = *p;
#pragma unroll
    for (int i = 0; i < 4; ++i) v[i] = rs2 * v[i] + c2;
    *p = v;
  }
}

extern "C" void kernel_launch(void* const* d_in, const int* in_sizes, int n_in,
                              void* d_out, int out_size, void* d_ws, size_t ws_size,
                              hipStream_t stream) {
  const float* x  = (const float*)d_in[0];
  const float* s1 = (const float*)d_in[1];
  const float* g1 = (const float*)d_in[2];
  const float* w1 = (const float*)d_in[3];
  const float* b1 = (const float*)d_in[4];
  const float* s2 = (const float*)d_in[5];
  const float* g2 = (const float*)d_in[6];
  const float* w2 = (const float*)d_in[7];
  const float* b2 = (const float*)d_in[8];
  float* out = (float*)d_out;
  float* wsf = (float*)d_ws;
  unsigned short* a1 = (unsigned short*)((char*)d_ws + 2048);
  unsigned short* a2 = (unsigned short*)((char*)d_ws + 10240);

  if (ws_size < 16384) return;

  hipMemsetAsync(d_ws, 0, 1024, stream);  // zero per-sample stat lines
  k1<<<dim3(128, 16), 256, 0, stream>>>(x, w1, b1, s1, g1, w2, b2, s2, g2, wsf, a1, a2);
  k2<<<dim3(256, 16), 256, 0, stream>>>(x, a1, a2, wsf, wsf, out);
  k3<<<dim3(96, 16), 256, 0, stream>>>(out, wsf);
}